// Round 2
// baseline (2377.404 us; speedup 1.0000x reference)
//
#include <hip/hip_runtime.h>
#include <hip/hip_bf16.h>

typedef __attribute__((ext_vector_type(8))) short short8;
typedef __attribute__((ext_vector_type(4))) float float4v;
typedef __attribute__((ext_vector_type(2))) float float2v;

#define T_STEPS 256
#define BATCH   256
#define DIM     512
#define HID     512

__device__ __forceinline__ float bf2f(unsigned short u) {
  unsigned int v = ((unsigned int)u) << 16;
  union { unsigned int i; float f; } c; c.i = v; return c.f;
}
__device__ __forceinline__ unsigned short f2bf(float f) {
  union { float f; unsigned int i; } c; c.f = f;
  unsigned int x = c.i;
  x += 0x7fffu + ((x >> 16) & 1u);   // RNE
  return (unsigned short)(x >> 16);
}
__device__ __forceinline__ float sigm(float x) {
  return __builtin_amdgcn_rcpf(1.0f + __expf(-x));
}
__device__ __forceinline__ float tanh_(float x) {
  return 1.0f - 2.0f * __builtin_amdgcn_rcpf(1.0f + __expf(2.0f * x));
}

// ---------------- Encoder GEMM: C = act(A[M,K] @ B[K,N] + bias).
// A is f32 (A_F32=true) or bf16-ushort; B/bias are f32; C stored bf16.
// One wave computes a 32x32 tile, fp32 accumulation via MFMA.
template<bool RELU, bool A_F32>
__global__ void enc_gemm(const void* __restrict__ Av,
                         const float* __restrict__ Bw,
                         const float* __restrict__ bias,
                         unsigned short* __restrict__ C,
                         int M, int N, int K) {
  const int tid  = threadIdx.x;
  const int lane = tid & 63;
  const int r = lane & 15, q = lane >> 4;
  const int waveId = blockIdx.x * 4 + (tid >> 6);
  const int nT = N >> 5;
  const int m0 = (waveId / nT) << 5;
  const int n0 = (waveId % nT) << 5;
  float4v acc[2][2] = {};
  const int ks = K >> 5;
  for (int s = 0; s < ks; ++s) {
    short8 a[2], b[2];
#pragma unroll
    for (int mt = 0; mt < 2; ++mt) {
      const size_t off = (size_t)(m0 + mt * 16 + r) * K + s * 32 + q * 8;
      if (A_F32) {
        const float* A = (const float*)Av;
        const float4v lo = *(const float4v*)(A + off);
        const float4v hi = *(const float4v*)(A + off + 4);
        short8 f;
#pragma unroll
        for (int j = 0; j < 4; ++j) { f[j] = (short)f2bf(lo[j]); f[j + 4] = (short)f2bf(hi[j]); }
        a[mt] = f;
      } else {
        a[mt] = *(const short8*)((const unsigned short*)Av + off);
      }
    }
#pragma unroll
    for (int nt = 0; nt < 2; ++nt) {
      const int col = n0 + nt * 16 + r;
      short8 f;
#pragma unroll
      for (int j = 0; j < 8; ++j)
        f[j] = (short)f2bf(Bw[(size_t)(s * 32 + q * 8 + j) * N + col]);
      b[nt] = f;
    }
#pragma unroll
    for (int mt = 0; mt < 2; ++mt)
#pragma unroll
      for (int nt = 0; nt < 2; ++nt)
        acc[mt][nt] = __builtin_amdgcn_mfma_f32_16x16x32_bf16(a[mt], b[nt], acc[mt][nt], 0, 0, 0);
  }
#pragma unroll
  for (int nt = 0; nt < 2; ++nt) {
    const float bv = bias[n0 + nt * 16 + r];
#pragma unroll
    for (int mt = 0; mt < 2; ++mt)
#pragma unroll
      for (int i = 0; i < 4; ++i) {
        float v = acc[mt][nt][i] + bv;
        if (RELU) v = fmaxf(v, 0.0f);
        C[(size_t)(m0 + mt * 16 + q * 4 + i) * N + n0 + nt * 16 + r] = f2bf(v);
      }
  }
}

// ---------------- Persistent recurrent kernel.
// 256 WGs = 8 groups x 32. Group g: batches [32g,32g+32). WG rank: h in [16*rank,16*rank+16)
// => gate cols {h, h+512, h+1024, h+1536}. gate_w slice (f32 -> bf16 once) held in
// REGISTERS (Bf[4][8], 128 VGPR). Waves split K=1024 (waves 0,1: comp; 2,3: hx).
// Partial gates reduced via LDS. cx in f32 registers for all 256 steps; hx feedback
// via bf16 global double buffer, sc1 (device-coherent) relaxed atomics, NO fences.
//
// R2 sync restructure (latency pass):
//  - waves 2,3 poll the group counter DIRECTLY (all lanes, same addr -> 1 coalesced
//    LLC req/wave) and go straight to hx loads; no release __syncthreads hop.
//  - per-WAVE arrive: after own stores drain (asm vmcnt(0)), lane 0 fire-and-forget
//    fetch_add; target 128 arrivals/step (4 waves x 32 WGs). Removes pre-arrive
//    __syncthreads convergence from the critical path.
//  - comp prefetch issued at the TOP of the step (drains under the hx wave's longer
//    poll+load phase instead of gating the arrival).
// Single LDS buffer stays safe: S2 separates reduce-reads(t) from partial-writes(t+1).
// Progress/order argument: a wave arrives for step t only after passing poll(t)
// (count >= 128t), so count >= 128t implies ALL 128 waves completed step t-1 with
// their hx stores acked at the coherence point; sc1 loads cannot read stale cache.
__global__ __launch_bounds__(256, 1) void qlstm_rec(
    const unsigned short* __restrict__ comp,  // [T*B, 512] bf16 (from enc3)
    const float* __restrict__ gw,             // [1024, 2048] f32
    const float* __restrict__ gb,             // [2048] f32
    const float* __restrict__ sw1, const float* __restrict__ sb1,
    const float* __restrict__ sw2, const float* __restrict__ sb2,
    unsigned short* __restrict__ hxbuf,       // 2 * [256,512] bf16 (buf0 pre-zeroed)
    unsigned int* __restrict__ bar,           // 8 groups * 16 u32 (pre-zeroed)
    float* __restrict__ out)                  // stacked[256,256,512] | hx[256,512] | cx[256,512]
{
  __shared__ float lds_g[4][32][68];  // [wave][batch][gatecol], +4 pad vs 64
  const int tid  = threadIdx.x;
  const int lane = tid & 63;
  const int wv   = tid >> 6;
  const int r = lane & 15, q = lane >> 4;
  const int gid  = blockIdx.x & 7;
  const int rank = blockIdx.x >> 3;
  const int b0 = gid << 5;
  const int h0 = rank << 4;

  // ----- constant sampler mask (value-invariant across timesteps) -----
  float t1[8];
#pragma unroll
  for (int j = 0; j < 8; ++j) {
    float s = sb1[j];
#pragma unroll
    for (int k = 0; k < 4; ++k) s += sw1[k * 8 + j];
    t1[j] = tanhf(s);
  }
  float s2[4];
#pragma unroll
  for (int c = 0; c < 4; ++c) {
    float s = sb2[c];
#pragma unroll
    for (int j = 0; j < 8; ++j) s += t1[j] * sw2[j * 4 + c];
    s2[c] = s;
  }
  const float mx = fmaxf(fmaxf(s2[0], s2[1]), fmaxf(s2[2], s2[3]));
  const float e0 = __expf(s2[0] - mx), e1 = __expf(s2[1] - mx);
  const float e2 = __expf(s2[2] - mx), e3 = __expf(s2[3] - mx);
  const float inv = 1.0f / (e0 + e1 + e2 + e3);
  const float m0f = e0 * inv, m1f = e1 * inv, m2f = e2 * inv, m3f = e3 * inv;

  // ----- persistent B fragments: gate_w[kbase..kbase+256, cols], f32 -> bf16 once -----
  short8 Bf[4][8];
  const int kbase = wv << 8;
#pragma unroll
  for (int nt = 0; nt < 4; ++nt) {
    const int col = nt * 512 + h0 + r;
#pragma unroll
    for (int s = 0; s < 8; ++s) {
      short8 f;
      const int kk = kbase + s * 32 + q * 8;
#pragma unroll
      for (int j = 0; j < 8; ++j)
        f[j] = (short)f2bf(gw[(size_t)(kk + j) * 2048 + col]);
      Bf[nt][s] = f;
    }
  }

  // ----- per-thread LSTM cell ownership: (bl, hj = 2hp / 2hp+1) -----
  const int bl = tid & 31;
  const int hp = tid >> 5;
  float bias_v[2][4];
#pragma unroll
  for (int u = 0; u < 2; ++u)
#pragma unroll
    for (int gt = 0; gt < 4; ++gt)
      bias_v[u][gt] = gb[gt * 512 + h0 + 2 * hp + u];
  float cxv[2] = {0.0f, 0.0f};
  float2v hx_last = {0.0f, 0.0f};

  const unsigned short* hx0p = hxbuf;
  const unsigned short* hx1p = hxbuf + BATCH * HID;
  unsigned int* barp = bar + gid * 16;

  // per-thread hx fragment base offsets (waves 2,3 only; 0 for others, unused)
  const int colb = ((wv >= 2) ? (wv - 2) : 0) * 256 + q * 8;
  const size_t hxoff0 = (size_t)(b0 + r) * HID + colb;
  const size_t hxoff1 = hxoff0 + (size_t)16 * HID;

  short8 aC[2][8], aN[2][8];
  if (wv < 2) {  // preload comp frags for t=0
#pragma unroll
    for (int s = 0; s < 8; ++s)
#pragma unroll
      for (int mt = 0; mt < 2; ++mt)
        aC[mt][s] = *(const short8*)(comp + (size_t)(b0 + mt * 16 + r) * DIM + kbase + s * 32 + q * 8);
  }

  auto step = [&](int t, short8 (&acur)[2][8], short8 (&anext)[2][8]) {
    const unsigned short* hxr = (t & 1) ? hx1p : hx0p;
    unsigned short* hxw = (unsigned short*)((t & 1) ? hx0p : hx1p);
    float4v acc[2][4] = {};
    if (wv < 2) {
      // issue next-step comp prefetch FIRST (drains under waves 2,3's longer phase;
      // keeps it off the arrival path)
      const int tn = (t < T_STEPS - 1) ? (t + 1) : t;
#pragma unroll
      for (int s = 0; s < 8; ++s)
#pragma unroll
        for (int mt = 0; mt < 2; ++mt)
          anext[mt][s] = *(const short8*)(comp + (size_t)(tn * BATCH + b0 + mt * 16 + r) * DIM + kbase + s * 32 + q * 8);
#pragma unroll
      for (int s = 0; s < 8; ++s)
#pragma unroll
        for (int mt = 0; mt < 2; ++mt)
#pragma unroll
          for (int nt = 0; nt < 4; ++nt)
            acc[mt][nt] = __builtin_amdgcn_mfma_f32_16x16x32_bf16(acur[mt][s], Bf[nt][s], acc[mt][nt], 0, 0, 0);
    } else {
      // direct poll by the consumer waves (uniform across lanes; 1 coalesced req/wave)
      const unsigned int tgt = 128u * (unsigned int)t;
      while (__hip_atomic_load(barp, __ATOMIC_RELAXED, __HIP_MEMORY_SCOPE_AGENT) < tgt) {}
      // device-coherent (sc1) hx loads: bypass non-coherent L2, read coherence point.
#pragma unroll
      for (int s = 0; s < 8; ++s) {
        {
          const unsigned long long* p = (const unsigned long long*)(hxr + hxoff0 + s * 32);
          union { unsigned long long u[2]; short8 s8; } x;
          x.u[0] = __hip_atomic_load((unsigned long long*)p,     __ATOMIC_RELAXED, __HIP_MEMORY_SCOPE_AGENT);
          x.u[1] = __hip_atomic_load((unsigned long long*)p + 1, __ATOMIC_RELAXED, __HIP_MEMORY_SCOPE_AGENT);
          acur[0][s] = x.s8;
        }
        {
          const unsigned long long* p = (const unsigned long long*)(hxr + hxoff1 + s * 32);
          union { unsigned long long u[2]; short8 s8; } x;
          x.u[0] = __hip_atomic_load((unsigned long long*)p,     __ATOMIC_RELAXED, __HIP_MEMORY_SCOPE_AGENT);
          x.u[1] = __hip_atomic_load((unsigned long long*)p + 1, __ATOMIC_RELAXED, __HIP_MEMORY_SCOPE_AGENT);
          acur[1][s] = x.s8;
        }
      }
#pragma unroll
      for (int s = 0; s < 8; ++s)
#pragma unroll
        for (int mt = 0; mt < 2; ++mt)
#pragma unroll
          for (int nt = 0; nt < 4; ++nt)
            acc[mt][nt] = __builtin_amdgcn_mfma_f32_16x16x32_bf16(acur[mt][s], Bf[nt][s], acc[mt][nt], 0, 0, 0);
    }
    // K-partial reduction through LDS
#pragma unroll
    for (int mt = 0; mt < 2; ++mt)
#pragma unroll
      for (int nt = 0; nt < 4; ++nt)
#pragma unroll
        for (int i = 0; i < 4; ++i)
          lds_g[wv][mt * 16 + q * 4 + i][nt * 16 + r] = acc[mt][nt][i];
    __syncthreads();  // S1: all partials visible
    float ga[2][4];
#pragma unroll
    for (int u = 0; u < 2; ++u)
#pragma unroll
      for (int gt = 0; gt < 4; ++gt) ga[u][gt] = bias_v[u][gt];
#pragma unroll
    for (int w = 0; w < 4; ++w)
#pragma unroll
      for (int gt = 0; gt < 4; ++gt) {
        const float2v pr = *(const float2v*)&lds_g[w][bl][gt * 16 + 2 * hp];
        ga[0][gt] += pr[0]; ga[1][gt] += pr[1];
      }
    float hxf[2];
#pragma unroll
    for (int u = 0; u < 2; ++u) {
      const float f = sigm(ga[u][0]) * m0f;
      const float i = sigm(ga[u][1]) * m1f;
      const float g = tanh_(ga[u][2]) * m2f;
      const float o = sigm(ga[u][3]) * m3f;
      const float c = f * cxv[u] + i * g;
      cxv[u] = c;
      hxf[u] = o * tanh_(c);
    }
    hx_last[0] = hxf[0]; hx_last[1] = hxf[1];
    const unsigned int hx_pack = (unsigned int)f2bf(hxf[0]) | ((unsigned int)f2bf(hxf[1]) << 16);
    const int hcol = h0 + 2 * hp;
    // device-coherent (sc1) hx store: write-through to coherence point.
    __hip_atomic_store((unsigned int*)(hxw + (size_t)(b0 + bl) * HID + hcol), hx_pack,
                       __ATOMIC_RELAXED, __HIP_MEMORY_SCOPE_AGENT);
    *(float2v*)(out + (size_t)(t * BATCH + b0 + bl) * HID + hcol) = hx_last;    // f32 output
    // per-wave arrive: drain OWN stores to the coherence point, then fire-and-forget.
    asm volatile("s_waitcnt vmcnt(0)" ::: "memory");
    if ((t < T_STEPS - 1) && lane == 0)
      __hip_atomic_fetch_add(barp, 1u, __ATOMIC_RELAXED, __HIP_MEMORY_SCOPE_AGENT);
    __syncthreads();  // S2: reduce-reads(t) done before next step's LDS partial writes
  };

#pragma unroll 1
  for (int t = 0; t < T_STEPS; t += 2) {
    step(t, aC, aN);
    step(t + 1, aN, aC);
  }

  // final hx, cx (f32)
  const int hcol = h0 + 2 * hp;
  const size_t base = (size_t)T_STEPS * BATCH * HID;
  *(float2v*)(out + base + (size_t)(b0 + bl) * HID + hcol) = hx_last;
  float2v cxo = {cxv[0], cxv[1]};
  *(float2v*)(out + base + (size_t)BATCH * HID + (size_t)(b0 + bl) * HID + hcol) = cxo;
}

extern "C" void kernel_launch(void* const* d_in, const int* in_sizes, int n_in,
                              void* d_out, int out_size, void* d_ws, size_t ws_size,
                              hipStream_t stream) {
  const float* x   = (const float*)d_in[0];
  const float* w1  = (const float*)d_in[1];
  const float* b1  = (const float*)d_in[2];
  const float* w2  = (const float*)d_in[3];
  const float* b2  = (const float*)d_in[4];
  const float* w3  = (const float*)d_in[5];
  const float* b3  = (const float*)d_in[6];
  const float* gw  = (const float*)d_in[7];
  const float* gb  = (const float*)d_in[8];
  const float* sw1 = (const float*)d_in[9];
  const float* sb1 = (const float*)d_in[10];
  const float* sw2 = (const float*)d_in[11];
  const float* sb2 = (const float*)d_in[12];
  float* out = (float*)d_out;

  char* ws = (char*)d_ws;
  unsigned short* comp = (unsigned short*)ws;                               // 67,108,864 B (bf16)
  unsigned short* hxb  = (unsigned short*)(ws + (size_t)67108864);          // 524,288 B
  unsigned int*   bar  = (unsigned int*)(ws + (size_t)67108864 + 524288);   // 512 B
  // h1/h2 bf16 scratch lives at the front of d_out (135 MB f32 buffer); dead after
  // enc3 and fully rewritten by qlstm_rec's stacked output (same-stream ordered).
  unsigned short* h1 = (unsigned short*)d_out;                              // 16,777,216 B
  unsigned short* h2 = h1 + (size_t)65536 * 128;                            //  8,388,608 B

  hipMemsetAsync(hxb, 0, (size_t)BATCH * HID * 2, stream);  // hx(0) = 0 (buf0 only)
  hipMemsetAsync(bar, 0, 512, stream);                      // barrier counters

  enc_gemm<true , true ><<<dim3(2048), 256, 0, stream>>>(x,  w1, b1, h1,   65536, 128, 512);
  enc_gemm<true , false><<<dim3(1024), 256, 0, stream>>>(h1, w2, b2, h2,   65536,  64, 128);
  enc_gemm<false, false><<<dim3(8192), 256, 0, stream>>>(h2, w3, b3, comp, 65536, 512,  64);

  qlstm_rec<<<dim3(256), 256, 0, stream>>>(comp, gw, gb, sw1, sb1, sw2, sb2, hxb, bar, out);
}

// Round 3
// 1544.009 us; speedup vs baseline: 1.5398x; 1.5398x over previous
//
#include <hip/hip_runtime.h>
#include <hip/hip_bf16.h>

typedef __attribute__((ext_vector_type(8))) short short8;
typedef __attribute__((ext_vector_type(4))) float float4v;
typedef __attribute__((ext_vector_type(2))) float float2v;

#define T_STEPS 256
#define BATCH   256
#define DIM     512
#define HID     512

__device__ __forceinline__ float bf2f(unsigned short u) {
  unsigned int v = ((unsigned int)u) << 16;
  union { unsigned int i; float f; } c; c.i = v; return c.f;
}
__device__ __forceinline__ unsigned short f2bf(float f) {
  union { float f; unsigned int i; } c; c.f = f;
  unsigned int x = c.i;
  x += 0x7fffu + ((x >> 16) & 1u);   // RNE
  return (unsigned short)(x >> 16);
}
__device__ __forceinline__ float sigm(float x) {
  return __builtin_amdgcn_rcpf(1.0f + __expf(-x));
}
__device__ __forceinline__ float tanh_(float x) {
  return 1.0f - 2.0f * __builtin_amdgcn_rcpf(1.0f + __expf(2.0f * x));
}

// ---------------- Encoder GEMM: C = act(A[M,K] @ B[K,N] + bias).
// A is f32 (A_F32=true) or bf16-ushort; B/bias are f32; C stored bf16.
// One wave computes a 32x32 tile, fp32 accumulation via MFMA.
template<bool RELU, bool A_F32>
__global__ void enc_gemm(const void* __restrict__ Av,
                         const float* __restrict__ Bw,
                         const float* __restrict__ bias,
                         unsigned short* __restrict__ C,
                         int M, int N, int K) {
  const int tid  = threadIdx.x;
  const int lane = tid & 63;
  const int r = lane & 15, q = lane >> 4;
  const int waveId = blockIdx.x * 4 + (tid >> 6);
  const int nT = N >> 5;
  const int m0 = (waveId / nT) << 5;
  const int n0 = (waveId % nT) << 5;
  float4v acc[2][2] = {};
  const int ks = K >> 5;
  for (int s = 0; s < ks; ++s) {
    short8 a[2], b[2];
#pragma unroll
    for (int mt = 0; mt < 2; ++mt) {
      const size_t off = (size_t)(m0 + mt * 16 + r) * K + s * 32 + q * 8;
      if (A_F32) {
        const float* A = (const float*)Av;
        const float4v lo = *(const float4v*)(A + off);
        const float4v hi = *(const float4v*)(A + off + 4);
        short8 f;
#pragma unroll
        for (int j = 0; j < 4; ++j) { f[j] = (short)f2bf(lo[j]); f[j + 4] = (short)f2bf(hi[j]); }
        a[mt] = f;
      } else {
        a[mt] = *(const short8*)((const unsigned short*)Av + off);
      }
    }
#pragma unroll
    for (int nt = 0; nt < 2; ++nt) {
      const int col = n0 + nt * 16 + r;
      short8 f;
#pragma unroll
      for (int j = 0; j < 8; ++j)
        f[j] = (short)f2bf(Bw[(size_t)(s * 32 + q * 8 + j) * N + col]);
      b[nt] = f;
    }
#pragma unroll
    for (int mt = 0; mt < 2; ++mt)
#pragma unroll
      for (int nt = 0; nt < 2; ++nt)
        acc[mt][nt] = __builtin_amdgcn_mfma_f32_16x16x32_bf16(a[mt], b[nt], acc[mt][nt], 0, 0, 0);
  }
#pragma unroll
  for (int nt = 0; nt < 2; ++nt) {
    const float bv = bias[n0 + nt * 16 + r];
#pragma unroll
    for (int mt = 0; mt < 2; ++mt)
#pragma unroll
      for (int i = 0; i < 4; ++i) {
        float v = acc[mt][nt][i] + bv;
        if (RELU) v = fmaxf(v, 0.0f);
        C[(size_t)(m0 + mt * 16 + q * 4 + i) * N + n0 + nt * 16 + r] = f2bf(v);
      }
  }
}

// ---------------- Persistent recurrent kernel.
// 256 WGs = 8 groups x 32. Group g: batches [32g,32g+32). WG rank: h in [16*rank,16*rank+16)
// => gate cols {h, h+512, h+1024, h+1536}. gate_w slice (f32 -> bf16 once) held in
// REGISTERS (Bf[4][8], 128 VGPR). Waves split K=1024 (waves 0,1: comp; 2,3: hx).
// Partial gates reduced via LDS. cx in f32 registers for all 256 steps; hx feedback
// via bf16 global double buffer, sc1 (device-coherent) relaxed atomics, NO fences.
//
// R3 sync: per-WG FLAG ARRAY (no central counter — R2 showed same-address RMWs
// serialize at the LLC bank and are the dominant sync cost).
//  - flags[gid][rank], padded 64B apart: each producer WG writes ONLY its own line.
//  - publisher = last-arriving wave of the WG (monotonic LDS fetch_add; the wave
//    seeing old==4t+3 publishes t+1 with one relaxed sc1 store) right after its own
//    vmcnt(0) drain — no pre-publish __syncthreads fan-out on the critical path.
//  - consumers: wave2 polls ranks 0-15 (its hx cols 0-255), wave3 ranks 16-31;
//    lane L reads flag[L&15] (16 distinct lines), __all(f>=t). Read-only poll on
//    lines nobody RMWs -> no serialization. Waves 0/1 never poll.
// Order argument: flag[gid][r]=t+1 is stored only after ALL 4 waves of WG(gid,r)
// have vmcnt-drained their hx(t) sc1 stores (acked at the coherence point). A
// consumer that observes flag>=t+1 then issues sc1 hx loads, which read the
// coherence point directly (no cached stale copies anywhere).
__global__ __launch_bounds__(256, 1) void qlstm_rec(
    const unsigned short* __restrict__ comp,  // [T*B, 512] bf16 (from enc3)
    const float* __restrict__ gw,             // [1024, 2048] f32
    const float* __restrict__ gb,             // [2048] f32
    const float* __restrict__ sw1, const float* __restrict__ sb1,
    const float* __restrict__ sw2, const float* __restrict__ sb2,
    unsigned short* __restrict__ hxbuf,       // 2 * [256,512] bf16 (buf0 pre-zeroed)
    unsigned int* __restrict__ bar,           // flags: 8 groups * 32 ranks * 16 u32 (pre-zeroed)
    float* __restrict__ out)                  // stacked[256,256,512] | hx[256,512] | cx[256,512]
{
  __shared__ float lds_g[4][32][68];  // [wave][batch][gatecol], +4 pad vs 64
  __shared__ unsigned int arr_cnt;    // monotonic per-step wave-arrival counter
  const int tid  = threadIdx.x;
  const int lane = tid & 63;
  const int wv   = tid >> 6;
  const int r = lane & 15, q = lane >> 4;
  const int gid  = blockIdx.x & 7;
  const int rank = blockIdx.x >> 3;
  const int b0 = gid << 5;
  const int h0 = rank << 4;

  if (tid == 0) arr_cnt = 0;

  // ----- constant sampler mask (value-invariant across timesteps) -----
  float t1[8];
#pragma unroll
  for (int j = 0; j < 8; ++j) {
    float s = sb1[j];
#pragma unroll
    for (int k = 0; k < 4; ++k) s += sw1[k * 8 + j];
    t1[j] = tanhf(s);
  }
  float s2[4];
#pragma unroll
  for (int c = 0; c < 4; ++c) {
    float s = sb2[c];
#pragma unroll
    for (int j = 0; j < 8; ++j) s += t1[j] * sw2[j * 4 + c];
    s2[c] = s;
  }
  const float mx = fmaxf(fmaxf(s2[0], s2[1]), fmaxf(s2[2], s2[3]));
  const float e0 = __expf(s2[0] - mx), e1 = __expf(s2[1] - mx);
  const float e2 = __expf(s2[2] - mx), e3 = __expf(s2[3] - mx);
  const float inv = 1.0f / (e0 + e1 + e2 + e3);
  const float m0f = e0 * inv, m1f = e1 * inv, m2f = e2 * inv, m3f = e3 * inv;

  // ----- persistent B fragments: gate_w[kbase..kbase+256, cols], f32 -> bf16 once -----
  short8 Bf[4][8];
  const int kbase = wv << 8;
#pragma unroll
  for (int nt = 0; nt < 4; ++nt) {
    const int col = nt * 512 + h0 + r;
#pragma unroll
    for (int s = 0; s < 8; ++s) {
      short8 f;
      const int kk = kbase + s * 32 + q * 8;
#pragma unroll
      for (int j = 0; j < 8; ++j)
        f[j] = (short)f2bf(gw[(size_t)(kk + j) * 2048 + col]);
      Bf[nt][s] = f;
    }
  }

  // ----- per-thread LSTM cell ownership: (bl, hj = 2hp / 2hp+1) -----
  const int bl = tid & 31;
  const int hp = tid >> 5;
  float bias_v[2][4];
#pragma unroll
  for (int u = 0; u < 2; ++u)
#pragma unroll
    for (int gt = 0; gt < 4; ++gt)
      bias_v[u][gt] = gb[gt * 512 + h0 + 2 * hp + u];
  float cxv[2] = {0.0f, 0.0f};
  float2v hx_last = {0.0f, 0.0f};

  const unsigned short* hx0p = hxbuf;
  const unsigned short* hx1p = hxbuf + BATCH * HID;

  // flag layout: bar[gid*512 + rank*16] (64B stride per rank)
  unsigned int* gflags = bar + gid * 512;
  unsigned int* myflag = gflags + rank * 16;
  // consumer poll address: wave2 -> ranks 0-15, wave3 -> ranks 16-31 (its hx cols)
  unsigned int* pollp = gflags + (((wv >= 2 ? wv - 2 : 0) * 16) + (lane & 15)) * 16;

  // per-thread hx fragment base offsets (waves 2,3 only; 0 for others, unused)
  const int colb = ((wv >= 2) ? (wv - 2) : 0) * 256 + q * 8;
  const size_t hxoff0 = (size_t)(b0 + r) * HID + colb;
  const size_t hxoff1 = hxoff0 + (size_t)16 * HID;

  short8 aC[2][8], aN[2][8];
  if (wv < 2) {  // preload comp frags for t=0
#pragma unroll
    for (int s = 0; s < 8; ++s)
#pragma unroll
      for (int mt = 0; mt < 2; ++mt)
        aC[mt][s] = *(const short8*)(comp + (size_t)(b0 + mt * 16 + r) * DIM + kbase + s * 32 + q * 8);
  }
  __syncthreads();  // arr_cnt init visible

  auto step = [&](int t, short8 (&acur)[2][8], short8 (&anext)[2][8]) {
    const unsigned short* hxr = (t & 1) ? hx1p : hx0p;
    unsigned short* hxw = (unsigned short*)((t & 1) ? hx0p : hx1p);
    float4v acc[2][4] = {};
    if (wv < 2) {
      // issue next-step comp prefetch first (L2-resident; drains long before the
      // end-of-step vmcnt(0))
      const int tn = (t < T_STEPS - 1) ? (t + 1) : t;
#pragma unroll
      for (int s = 0; s < 8; ++s)
#pragma unroll
        for (int mt = 0; mt < 2; ++mt)
          anext[mt][s] = *(const short8*)(comp + (size_t)(tn * BATCH + b0 + mt * 16 + r) * DIM + kbase + s * 32 + q * 8);
#pragma unroll
      for (int s = 0; s < 8; ++s)
#pragma unroll
        for (int mt = 0; mt < 2; ++mt)
#pragma unroll
          for (int nt = 0; nt < 4; ++nt)
            acc[mt][nt] = __builtin_amdgcn_mfma_f32_16x16x32_bf16(acur[mt][s], Bf[nt][s], acc[mt][nt], 0, 0, 0);
    } else {
      // poll ONLY the 16 producer ranks this wave consumes; read-only sc1 loads on
      // 16 distinct (64B-padded) lines — no RMW interference anywhere.
      const unsigned int tgt = (unsigned int)t;
      while (true) {
        const unsigned int f = __hip_atomic_load(pollp, __ATOMIC_RELAXED, __HIP_MEMORY_SCOPE_AGENT);
        if (__all((int)(f >= tgt))) break;
      }
      // device-coherent (sc1) hx loads: bypass non-coherent caches.
#pragma unroll
      for (int s = 0; s < 8; ++s) {
        {
          const unsigned long long* p = (const unsigned long long*)(hxr + hxoff0 + s * 32);
          union { unsigned long long u[2]; short8 s8; } x;
          x.u[0] = __hip_atomic_load((unsigned long long*)p,     __ATOMIC_RELAXED, __HIP_MEMORY_SCOPE_AGENT);
          x.u[1] = __hip_atomic_load((unsigned long long*)p + 1, __ATOMIC_RELAXED, __HIP_MEMORY_SCOPE_AGENT);
          acur[0][s] = x.s8;
        }
        {
          const unsigned long long* p = (const unsigned long long*)(hxr + hxoff1 + s * 32);
          union { unsigned long long u[2]; short8 s8; } x;
          x.u[0] = __hip_atomic_load((unsigned long long*)p,     __ATOMIC_RELAXED, __HIP_MEMORY_SCOPE_AGENT);
          x.u[1] = __hip_atomic_load((unsigned long long*)p + 1, __ATOMIC_RELAXED, __HIP_MEMORY_SCOPE_AGENT);
          acur[1][s] = x.s8;
        }
      }
#pragma unroll
      for (int s = 0; s < 8; ++s)
#pragma unroll
        for (int mt = 0; mt < 2; ++mt)
#pragma unroll
          for (int nt = 0; nt < 4; ++nt)
            acc[mt][nt] = __builtin_amdgcn_mfma_f32_16x16x32_bf16(acur[mt][s], Bf[nt][s], acc[mt][nt], 0, 0, 0);
    }
    // K-partial reduction through LDS
#pragma unroll
    for (int mt = 0; mt < 2; ++mt)
#pragma unroll
      for (int nt = 0; nt < 4; ++nt)
#pragma unroll
        for (int i = 0; i < 4; ++i)
          lds_g[wv][mt * 16 + q * 4 + i][nt * 16 + r] = acc[mt][nt][i];
    __syncthreads();  // S1: all partials visible
    float ga[2][4];
#pragma unroll
    for (int u = 0; u < 2; ++u)
#pragma unroll
      for (int gt = 0; gt < 4; ++gt) ga[u][gt] = bias_v[u][gt];
#pragma unroll
    for (int w = 0; w < 4; ++w)
#pragma unroll
      for (int gt = 0; gt < 4; ++gt) {
        const float2v pr = *(const float2v*)&lds_g[w][bl][gt * 16 + 2 * hp];
        ga[0][gt] += pr[0]; ga[1][gt] += pr[1];
      }
    float hxf[2];
#pragma unroll
    for (int u = 0; u < 2; ++u) {
      const float f = sigm(ga[u][0]) * m0f;
      const float i = sigm(ga[u][1]) * m1f;
      const float g = tanh_(ga[u][2]) * m2f;
      const float o = sigm(ga[u][3]) * m3f;
      const float c = f * cxv[u] + i * g;
      cxv[u] = c;
      hxf[u] = o * tanh_(c);
    }
    hx_last[0] = hxf[0]; hx_last[1] = hxf[1];
    const unsigned int hx_pack = (unsigned int)f2bf(hxf[0]) | ((unsigned int)f2bf(hxf[1]) << 16);
    const int hcol = h0 + 2 * hp;
    // device-coherent (sc1) hx store: write-through to coherence point.
    __hip_atomic_store((unsigned int*)(hxw + (size_t)(b0 + bl) * HID + hcol), hx_pack,
                       __ATOMIC_RELAXED, __HIP_MEMORY_SCOPE_AGENT);
    *(float2v*)(out + (size_t)(t * BATCH + b0 + bl) * HID + hcol) = hx_last;    // f32 output
    // per-wave arrive: drain OWN stores (sc1 ack = coherence-point visible), then
    // monotonic LDS count; the LAST wave publishes the per-WG flag immediately.
    asm volatile("s_waitcnt vmcnt(0)" ::: "memory");
    if (lane == 0) {
      const unsigned int old =
          __hip_atomic_fetch_add(&arr_cnt, 1u, __ATOMIC_RELAXED, __HIP_MEMORY_SCOPE_WORKGROUP);
      if (old == (unsigned int)(4 * t + 3) && t < T_STEPS - 1)
        __hip_atomic_store(myflag, (unsigned int)(t + 1), __ATOMIC_RELAXED, __HIP_MEMORY_SCOPE_AGENT);
    }
    __syncthreads();  // S2: reduce-reads(t) done before next step's LDS partial writes
  };

#pragma unroll 1
  for (int t = 0; t < T_STEPS; t += 2) {
    step(t, aC, aN);
    step(t + 1, aN, aC);
  }

  // final hx, cx (f32)
  const int hcol = h0 + 2 * hp;
  const size_t base = (size_t)T_STEPS * BATCH * HID;
  *(float2v*)(out + base + (size_t)(b0 + bl) * HID + hcol) = hx_last;
  float2v cxo = {cxv[0], cxv[1]};
  *(float2v*)(out + base + (size_t)BATCH * HID + (size_t)(b0 + bl) * HID + hcol) = cxo;
}

extern "C" void kernel_launch(void* const* d_in, const int* in_sizes, int n_in,
                              void* d_out, int out_size, void* d_ws, size_t ws_size,
                              hipStream_t stream) {
  const float* x   = (const float*)d_in[0];
  const float* w1  = (const float*)d_in[1];
  const float* b1  = (const float*)d_in[2];
  const float* w2  = (const float*)d_in[3];
  const float* b2  = (const float*)d_in[4];
  const float* w3  = (const float*)d_in[5];
  const float* b3  = (const float*)d_in[6];
  const float* gw  = (const float*)d_in[7];
  const float* gb  = (const float*)d_in[8];
  const float* sw1 = (const float*)d_in[9];
  const float* sb1 = (const float*)d_in[10];
  const float* sw2 = (const float*)d_in[11];
  const float* sb2 = (const float*)d_in[12];
  float* out = (float*)d_out;

  char* ws = (char*)d_ws;
  unsigned short* comp = (unsigned short*)ws;                               // 67,108,864 B (bf16)
  unsigned short* hxb  = (unsigned short*)(ws + (size_t)67108864);          // 524,288 B
  unsigned int*   bar  = (unsigned int*)(ws + (size_t)67108864 + 524288);   // 16,384 B flags
  // h1/h2 bf16 scratch lives at the front of d_out (135 MB f32 buffer); dead after
  // enc3 and fully rewritten by qlstm_rec's stacked output (same-stream ordered).
  unsigned short* h1 = (unsigned short*)d_out;                              // 16,777,216 B
  unsigned short* h2 = h1 + (size_t)65536 * 128;                            //  8,388,608 B

  hipMemsetAsync(hxb, 0, (size_t)BATCH * HID * 2, stream);  // hx(0) = 0 (buf0 only)
  hipMemsetAsync(bar, 0, 16384, stream);                    // flag array

  enc_gemm<true , true ><<<dim3(2048), 256, 0, stream>>>(x,  w1, b1, h1,   65536, 128, 512);
  enc_gemm<true , false><<<dim3(1024), 256, 0, stream>>>(h1, w2, b2, h2,   65536,  64, 128);
  enc_gemm<false, false><<<dim3(8192), 256, 0, stream>>>(h2, w3, b3, comp, 65536, 512,  64);

  qlstm_rec<<<dim3(256), 256, 0, stream>>>(comp, gw, gb, sw1, sb1, sw2, sb2, hxb, bar, out);
}